// Round 3
// baseline (1025.236 us; speedup 1.0000x reference)
//
#include <hip/hip_runtime.h>

#define NROWS 4096
#define NCLASS 50257
#define BLK 256

// Stage 1: one block per row, online softmax with RARE-RESCALE branch.
// The running max updates only ~log(iters) times, so the common path has no
// serial (m,l)-rescale chain: exp tree is independent of l, one add per iter.
// 2 float4s per iteration for MLP + halved loop overhead.
__global__ __launch_bounds__(BLK) void ce_row_kernel(
    const float* __restrict__ pred,
    const int* __restrict__ target,
    float* __restrict__ row_loss) {
    const int row = blockIdx.x;
    const float* __restrict__ p = pred + (size_t)row * NCLASS;
    const int tid = threadIdx.x;

    float m = -3.4e38f;
    float l = 0.0f;

    // Peel to 16B alignment (row stride 50257*4 B is only 4B-aligned on odd rows).
    const int head = (int)(((16u - (unsigned)((size_t)p & 15u)) & 15u) >> 2);
    if (tid < head) { m = p[tid]; l = 1.0f; }

    const float4* __restrict__ pv = (const float4*)(p + head);
    const int nvec = (NCLASS - head) >> 2;

    int i = tid;
    for (; i + BLK < nvec; i += 2 * BLK) {
        float4 a = pv[i];
        float4 b = pv[i + BLK];
        float am = fmaxf(fmaxf(a.x, a.y), fmaxf(a.z, a.w));
        float bm = fmaxf(fmaxf(b.x, b.y), fmaxf(b.z, b.w));
        float vm = fmaxf(am, bm);
        if (vm <= m) {
            // fast path (common): no rescale, exp-tree independent of l-chain
            float s = (__expf(a.x - m) + __expf(a.y - m))
                    + (__expf(a.z - m) + __expf(a.w - m))
                    + (__expf(b.x - m) + __expf(b.y - m))
                    + (__expf(b.z - m) + __expf(b.w - m));
            l += s;
        } else {
            // rare path: new max, rescale l
            float s = (__expf(a.x - vm) + __expf(a.y - vm))
                    + (__expf(a.z - vm) + __expf(a.w - vm))
                    + (__expf(b.x - vm) + __expf(b.y - vm))
                    + (__expf(b.z - vm) + __expf(b.w - vm));
            l = l * __expf(m - vm) + s;
            m = vm;
        }
    }
    // leftover single-float4 iterations
    for (; i < nvec; i += BLK) {
        float4 a = pv[i];
        float vm = fmaxf(fmaxf(a.x, a.y), fmaxf(a.z, a.w));
        float nm = fmaxf(m, vm);
        l = l * __expf(m - nm)
          + __expf(a.x - nm) + __expf(a.y - nm)
          + __expf(a.z - nm) + __expf(a.w - nm);
        m = nm;
    }
    // scalar tail (NCLASS % 4 residue)
    for (int j = head + (nvec << 2) + tid; j < NCLASS; j += BLK) {
        float x = p[j];
        float nm = fmaxf(m, x);
        l = l * __expf(m - nm) + __expf(x - nm);
        m = nm;
    }

    // wave-level reduce of (m, l)
    #pragma unroll
    for (int off = 32; off > 0; off >>= 1) {
        float om = __shfl_down(m, off, 64);
        float ol = __shfl_down(l, off, 64);
        float nm = fmaxf(m, om);
        l = l * __expf(m - nm) + ol * __expf(om - nm);
        m = nm;
    }

    // cross-wave reduce via LDS (4 waves)
    __shared__ float sm[BLK / 64];
    __shared__ float sl[BLK / 64];
    const int wave = tid >> 6;
    const int lane = tid & 63;
    if (lane == 0) { sm[wave] = m; sl[wave] = l; }
    __syncthreads();

    if (tid == 0) {
        m = sm[0]; l = sl[0];
        #pragma unroll
        for (int w = 1; w < BLK / 64; ++w) {
            float om = sm[w], ol = sl[w];
            float nm = fmaxf(m, om);
            l = l * __expf(m - nm) + ol * __expf(om - nm);
            m = nm;
        }
        const int t = target[row];
        row_loss[row] = -(p[t] - m - __logf(l));
    }
}

// Stage 2: single block sums 4096 per-row losses, writes scalar (overwrites poison).
__global__ __launch_bounds__(BLK) void ce_reduce_kernel(
    const float* __restrict__ row_loss,
    float* __restrict__ out) {
    const int tid = threadIdx.x;
    float s = 0.0f;
    for (int i = tid; i < NROWS; i += BLK) s += row_loss[i];

    #pragma unroll
    for (int off = 32; off > 0; off >>= 1) s += __shfl_down(s, off, 64);

    __shared__ float sw[BLK / 64];
    if ((tid & 63) == 0) sw[tid >> 6] = s;
    __syncthreads();

    if (tid == 0) {
        float t = 0.0f;
        #pragma unroll
        for (int w = 0; w < BLK / 64; ++w) t += sw[w];
        out[0] = t * (1.0f / (float)NROWS);
    }
}

extern "C" void kernel_launch(void* const* d_in, const int* in_sizes, int n_in,
                              void* d_out, int out_size, void* d_ws, size_t ws_size,
                              hipStream_t stream) {
    const float* pred = (const float*)d_in[0];
    const int* target = (const int*)d_in[1];
    float* out = (float*)d_out;
    float* row_loss = (float*)d_ws;   // 4096 floats = 16 KB scratch

    ce_row_kernel<<<NROWS, BLK, 0, stream>>>(pred, target, row_loss);
    ce_reduce_kernel<<<1, BLK, 0, stream>>>(row_loss, out);
}